// Round 1
// baseline (577.381 us; speedup 1.0000x reference)
//
#include <hip/hip_runtime.h>

#define N_NODES 100000
#define N_EDGES 1600000
#define IN_F 128
#define OUT_F 64
#define LN_EPS 1e-5f

// ---------------------------------------------------------------------------
// Kernel 1: support = x @ W        (x: [N,128] row-major, W: [128,64] k-major)
// Block = 256 threads = 4 waves. Each wave computes one node row per group
// iteration. W column for lane o cached in 128 VGPRs (loaded coalesced once
// per thread). x rows staged in LDS, read as broadcast float4 (ds_read_b128).
// ---------------------------------------------------------------------------
__global__ __launch_bounds__(256) void gemm_support(
    const float* __restrict__ x, const float* __restrict__ W,
    float* __restrict__ support) {
  __shared__ float xl[4 * IN_F];
  const int o = threadIdx.x & 63;
  const int wid = __builtin_amdgcn_readfirstlane(threadIdx.x >> 6);

  // W[:,o] -> registers (coalesced across lanes for each k)
  float wcol[IN_F];
#pragma unroll
  for (int k = 0; k < IN_F; ++k) wcol[k] = W[k * OUT_F + o];

  const int ngroups = N_NODES / 4;  // 25000, exact
  for (int g = blockIdx.x; g < ngroups; g += gridDim.x) {
    __syncthreads();  // protect xl reuse from previous iteration
    if (threadIdx.x < 128) {
      ((float4*)xl)[threadIdx.x] =
          ((const float4*)(x + (size_t)g * 4 * IN_F))[threadIdx.x];
    }
    __syncthreads();

    const float4* xr = (const float4*)(xl + wid * IN_F);
    float acc = 0.f;
#pragma unroll
    for (int k4 = 0; k4 < IN_F / 4; ++k4) {
      float4 xv = xr[k4];
      acc += xv.x * wcol[k4 * 4 + 0];
      acc += xv.y * wcol[k4 * 4 + 1];
      acc += xv.z * wcol[k4 * 4 + 2];
      acc += xv.w * wcol[k4 * 4 + 3];
    }
    support[((size_t)g * 4 + wid) * OUT_F + o] = acc;
  }
}

// ---------------------------------------------------------------------------
// Kernel 2: scatter  acc[dst] += w_e * support[src]
// One wave per edge: lane = output feature (OUT_F == wavefront == 64).
// Edge metadata is wave-uniform -> scalar loads. Native f32 atomic add.
// ---------------------------------------------------------------------------
__global__ __launch_bounds__(256) void scatter_edges(
    const float* __restrict__ support, const float* __restrict__ ew,
    const int* __restrict__ esrc, const int* __restrict__ edst,
    float* __restrict__ acc) {
  const int o = threadIdx.x & 63;
  const int wid = __builtin_amdgcn_readfirstlane(threadIdx.x >> 6);
  const int gw = blockIdx.x * 4 + wid;           // global wave id
  const int nw = gridDim.x * 4;                  // total waves

  for (int e = gw; e < N_EDGES; e += nw) {
    const int s = esrc[e];
    const int d = edst[e];
    const float w = ew[e];
    const float v = support[(size_t)s * OUT_F + o] * w;
    unsafeAtomicAdd(&acc[(size_t)d * OUT_F + o], v);
  }
}

// ---------------------------------------------------------------------------
// Kernel 3: finalize (in-place on acc/out):
//   v = acc + bias; LN over 64 features; ReLU; + x @ res_w.T + res_b
// One wave per node. res_w row for lane o cached in 128 VGPRs.
// ---------------------------------------------------------------------------
__global__ __launch_bounds__(256) void finalize(
    const float* __restrict__ x, const float* __restrict__ bias,
    const float* __restrict__ gamma, const float* __restrict__ beta,
    const float* __restrict__ res_w, const float* __restrict__ res_b,
    float* __restrict__ out) {
  __shared__ float xl[4 * IN_F];
  const int o = threadIdx.x & 63;
  const int wid = __builtin_amdgcn_readfirstlane(threadIdx.x >> 6);

  // res_w[o, :] -> registers (row-contiguous, float4 per lane)
  float rw[IN_F];
  const float4* rwrow = (const float4*)(res_w + (size_t)o * IN_F);
#pragma unroll
  for (int k4 = 0; k4 < IN_F / 4; ++k4) {
    float4 t = rwrow[k4];
    rw[k4 * 4 + 0] = t.x;
    rw[k4 * 4 + 1] = t.y;
    rw[k4 * 4 + 2] = t.z;
    rw[k4 * 4 + 3] = t.w;
  }
  const float bi = bias[o];
  const float ga = gamma[o];
  const float be = beta[o];
  const float rb = res_b[o];

  const int ngroups = N_NODES / 4;
  for (int g = blockIdx.x; g < ngroups; g += gridDim.x) {
    __syncthreads();
    if (threadIdx.x < 128) {
      ((float4*)xl)[threadIdx.x] =
          ((const float4*)(x + (size_t)g * 4 * IN_F))[threadIdx.x];
    }
    __syncthreads();

    const size_t n = (size_t)g * 4 + wid;
    float v = out[n * OUT_F + o] + bi;

    // wave-wide mean/var (butterfly over 64 lanes)
    float s = v, sq = v * v;
#pragma unroll
    for (int off = 32; off > 0; off >>= 1) {
      s += __shfl_xor(s, off, 64);
      sq += __shfl_xor(sq, off, 64);
    }
    const float mu = s * (1.f / 64.f);
    float var = sq * (1.f / 64.f) - mu * mu;
    const float r = rsqrtf(var + LN_EPS);
    float nrm = (v - mu) * r * ga + be;
    nrm = fmaxf(nrm, 0.f);

    // residual: dot(x[n,:], res_w[o,:])
    const float4* xr = (const float4*)(xl + wid * IN_F);
    float dot = 0.f;
#pragma unroll
    for (int k4 = 0; k4 < IN_F / 4; ++k4) {
      float4 xv = xr[k4];
      dot += xv.x * rw[k4 * 4 + 0];
      dot += xv.y * rw[k4 * 4 + 1];
      dot += xv.z * rw[k4 * 4 + 2];
      dot += xv.w * rw[k4 * 4 + 3];
    }
    out[n * OUT_F + o] = nrm + dot + rb;
  }
}

// ---------------------------------------------------------------------------
extern "C" void kernel_launch(void* const* d_in, const int* in_sizes, int n_in,
                              void* d_out, int out_size, void* d_ws,
                              size_t ws_size, hipStream_t stream) {
  const float* x       = (const float*)d_in[0];
  const float* weight  = (const float*)d_in[1];
  const float* bias    = (const float*)d_in[2];
  const float* gamma   = (const float*)d_in[3];
  const float* beta    = (const float*)d_in[4];
  const float* res_w   = (const float*)d_in[5];
  const float* res_b   = (const float*)d_in[6];
  const float* ew      = (const float*)d_in[7];
  const int*   esrc    = (const int*)d_in[8];
  const int*   edst    = (const int*)d_in[9];
  float* out = (float*)d_out;

  float* support = (float*)d_ws;  // N_NODES * OUT_F floats = 25.6 MB

  // zero the accumulator (d_out is poisoned 0xAA before every launch)
  hipMemsetAsync(out, 0, (size_t)N_NODES * OUT_F * sizeof(float), stream);

  gemm_support<<<2048, 256, 0, stream>>>(x, weight, support);
  scatter_edges<<<4096, 256, 0, stream>>>(support, ew, esrc, edst, out);
  finalize<<<2048, 256, 0, stream>>>(x, bias, gamma, beta, res_w, res_b, out);
}

// Round 2
// 468.602 us; speedup vs baseline: 1.2321x; 1.2321x over previous
//
#include <hip/hip_runtime.h>

#define N_NODES 100000
#define N_EDGES 1600000
#define IN_F 128
#define OUT_F 64
#define LN_EPS 1e-5f

#define SCAN_BLK 1024
#define N_SCAN_BLKS ((N_NODES + SCAN_BLK - 1) / SCAN_BLK)  // 98

// ---------------------------------------------------------------------------
// Kernel 1: support = x @ W   (unchanged from R1 — proven correct)
// ---------------------------------------------------------------------------
__global__ __launch_bounds__(256) void gemm_support(
    const float* __restrict__ x, const float* __restrict__ W,
    float* __restrict__ support) {
  __shared__ float xl[4 * IN_F];
  const int o = threadIdx.x & 63;
  const int wid = __builtin_amdgcn_readfirstlane(threadIdx.x >> 6);

  float wcol[IN_F];
#pragma unroll
  for (int k = 0; k < IN_F; ++k) wcol[k] = W[k * OUT_F + o];

  const int ngroups = N_NODES / 4;
  for (int g = blockIdx.x; g < ngroups; g += gridDim.x) {
    __syncthreads();
    if (threadIdx.x < 128) {
      ((float4*)xl)[threadIdx.x] =
          ((const float4*)(x + (size_t)g * 4 * IN_F))[threadIdx.x];
    }
    __syncthreads();

    const float4* xr = (const float4*)(xl + wid * IN_F);
    float acc = 0.f;
#pragma unroll
    for (int k4 = 0; k4 < IN_F / 4; ++k4) {
      float4 xv = xr[k4];
      acc += xv.x * wcol[k4 * 4 + 0];
      acc += xv.y * wcol[k4 * 4 + 1];
      acc += xv.z * wcol[k4 * 4 + 2];
      acc += xv.w * wcol[k4 * 4 + 3];
    }
    support[((size_t)g * 4 + wid) * OUT_F + o] = acc;
  }
}

// ---------------------------------------------------------------------------
// CSR build: histogram -> block scan -> partial scan -> add offsets -> reorder
// ---------------------------------------------------------------------------
__global__ __launch_bounds__(256) void histogram(const int* __restrict__ edst,
                                                 int* __restrict__ cnt) {
  const int stride = gridDim.x * blockDim.x;
  for (int i = blockIdx.x * blockDim.x + threadIdx.x; i < N_EDGES; i += stride)
    atomicAdd(&cnt[edst[i]], 1);
}

__global__ __launch_bounds__(SCAN_BLK) void scan_blocks(
    const int* __restrict__ cnt, int* __restrict__ row_ptr,
    int* __restrict__ partials) {
  __shared__ int sh[SCAN_BLK];
  const int i = blockIdx.x * SCAN_BLK + threadIdx.x;
  const int v = (i < N_NODES) ? cnt[i] : 0;
  sh[threadIdx.x] = v;
  __syncthreads();
  for (int off = 1; off < SCAN_BLK; off <<= 1) {
    int t = (threadIdx.x >= off) ? sh[threadIdx.x - off] : 0;
    __syncthreads();
    sh[threadIdx.x] += t;
    __syncthreads();
  }
  const int inc = sh[threadIdx.x];
  if (i < N_NODES) row_ptr[i] = inc - v;  // exclusive within block
  if (threadIdx.x == SCAN_BLK - 1) partials[blockIdx.x] = inc;
}

__global__ __launch_bounds__(128) void scan_partials(
    const int* __restrict__ partials, int* __restrict__ blockoff) {
  __shared__ int sh[128];
  const int t = threadIdx.x;
  const int v = (t < N_SCAN_BLKS) ? partials[t] : 0;
  sh[t] = v;
  __syncthreads();
  for (int off = 1; off < 128; off <<= 1) {
    int tmp = (t >= off) ? sh[t - off] : 0;
    __syncthreads();
    sh[t] += tmp;
    __syncthreads();
  }
  if (t < N_SCAN_BLKS) blockoff[t] = sh[t] - v;  // exclusive
}

__global__ __launch_bounds__(SCAN_BLK) void add_offsets(
    int* __restrict__ row_ptr, int* __restrict__ cursor,
    const int* __restrict__ blockoff) {
  const int i = blockIdx.x * SCAN_BLK + threadIdx.x;
  if (i < N_NODES) {
    const int v = row_ptr[i] + blockoff[blockIdx.x];
    row_ptr[i] = v;
    cursor[i] = v;
  }
  if (i == 0) row_ptr[N_NODES] = N_EDGES;
}

__global__ __launch_bounds__(256) void csr_scatter(
    const int* __restrict__ esrc, const int* __restrict__ edst,
    const float* __restrict__ ew, int* __restrict__ cursor,
    int2* __restrict__ csr) {
  const int stride = gridDim.x * blockDim.x;
  for (int i = blockIdx.x * blockDim.x + threadIdx.x; i < N_EDGES; i += stride) {
    const int d = edst[i];
    const int pos = atomicAdd(&cursor[d], 1);
    csr[pos] = make_int2(esrc[i], __float_as_int(ew[i]));
  }
}

// ---------------------------------------------------------------------------
// Gather: wave per node, lane = feature. Edge metadata via wave-uniform
// scalar loads (readfirstlane forces SGPR addressing); support rows gathered
// per-lane. Unrolled x4 with 2 accumulators for MLP. One store per node.
// ---------------------------------------------------------------------------
__global__ __launch_bounds__(256) void gather(
    const float* __restrict__ support, const int2* __restrict__ csr,
    const int* __restrict__ row_ptr, float* __restrict__ out) {
  const int o = threadIdx.x & 63;
  const int wid = threadIdx.x >> 6;
  const int gw = blockIdx.x * 4 + wid;
  const int nw = gridDim.x * 4;

  for (int n = gw; n < N_NODES; n += nw) {
    const int nu = __builtin_amdgcn_readfirstlane(n);
    const int beg = row_ptr[nu];
    const int end = row_ptr[nu + 1];
    float acc0 = 0.f, acc1 = 0.f;
    int e = beg;
    for (; e + 3 < end; e += 4) {
      const int2 a = csr[e], b = csr[e + 1], c = csr[e + 2], d = csr[e + 3];
      const float va = support[(size_t)a.x * OUT_F + o];
      const float vb = support[(size_t)b.x * OUT_F + o];
      const float vc = support[(size_t)c.x * OUT_F + o];
      const float vd = support[(size_t)d.x * OUT_F + o];
      acc0 = fmaf(va, __int_as_float(a.y), acc0);
      acc1 = fmaf(vb, __int_as_float(b.y), acc1);
      acc0 = fmaf(vc, __int_as_float(c.y), acc0);
      acc1 = fmaf(vd, __int_as_float(d.y), acc1);
    }
    for (; e < end; ++e) {
      const int2 a = csr[e];
      acc0 = fmaf(support[(size_t)a.x * OUT_F + o], __int_as_float(a.y), acc0);
    }
    out[(size_t)n * OUT_F + o] = acc0 + acc1;
  }
}

// ---------------------------------------------------------------------------
// Finalize (unchanged from R1): bias + LN(64) + ReLU + x @ res_w.T + res_b
// ---------------------------------------------------------------------------
__global__ __launch_bounds__(256) void finalize(
    const float* __restrict__ x, const float* __restrict__ bias,
    const float* __restrict__ gamma, const float* __restrict__ beta,
    const float* __restrict__ res_w, const float* __restrict__ res_b,
    float* __restrict__ out) {
  __shared__ float xl[4 * IN_F];
  const int o = threadIdx.x & 63;
  const int wid = __builtin_amdgcn_readfirstlane(threadIdx.x >> 6);

  float rw[IN_F];
  const float4* rwrow = (const float4*)(res_w + (size_t)o * IN_F);
#pragma unroll
  for (int k4 = 0; k4 < IN_F / 4; ++k4) {
    float4 t = rwrow[k4];
    rw[k4 * 4 + 0] = t.x;
    rw[k4 * 4 + 1] = t.y;
    rw[k4 * 4 + 2] = t.z;
    rw[k4 * 4 + 3] = t.w;
  }
  const float bi = bias[o];
  const float ga = gamma[o];
  const float be = beta[o];
  const float rb = res_b[o];

  const int ngroups = N_NODES / 4;
  for (int g = blockIdx.x; g < ngroups; g += gridDim.x) {
    __syncthreads();
    if (threadIdx.x < 128) {
      ((float4*)xl)[threadIdx.x] =
          ((const float4*)(x + (size_t)g * 4 * IN_F))[threadIdx.x];
    }
    __syncthreads();

    const size_t n = (size_t)g * 4 + wid;
    float v = out[n * OUT_F + o] + bi;

    float s = v, sq = v * v;
#pragma unroll
    for (int off = 32; off > 0; off >>= 1) {
      s += __shfl_xor(s, off, 64);
      sq += __shfl_xor(sq, off, 64);
    }
    const float mu = s * (1.f / 64.f);
    float var = sq * (1.f / 64.f) - mu * mu;
    const float r = rsqrtf(var + LN_EPS);
    float nrm = (v - mu) * r * ga + be;
    nrm = fmaxf(nrm, 0.f);

    const float4* xr = (const float4*)(xl + wid * IN_F);
    float dot = 0.f;
#pragma unroll
    for (int k4 = 0; k4 < IN_F / 4; ++k4) {
      float4 xv = xr[k4];
      dot += xv.x * rw[k4 * 4 + 0];
      dot += xv.y * rw[k4 * 4 + 1];
      dot += xv.z * rw[k4 * 4 + 2];
      dot += xv.w * rw[k4 * 4 + 3];
    }
    out[n * OUT_F + o] = nrm + dot + rb;
  }
}

// ---------------------------------------------------------------------------
extern "C" void kernel_launch(void* const* d_in, const int* in_sizes, int n_in,
                              void* d_out, int out_size, void* d_ws,
                              size_t ws_size, hipStream_t stream) {
  const float* x      = (const float*)d_in[0];
  const float* weight = (const float*)d_in[1];
  const float* bias   = (const float*)d_in[2];
  const float* gamma  = (const float*)d_in[3];
  const float* beta   = (const float*)d_in[4];
  const float* res_w  = (const float*)d_in[5];
  const float* res_b  = (const float*)d_in[6];
  const float* ew     = (const float*)d_in[7];
  const int*   esrc   = (const int*)d_in[8];
  const int*   edst   = (const int*)d_in[9];
  float* out = (float*)d_out;

  // Workspace layout (all 256B-aligned):
  char* ws = (char*)d_ws;
  size_t off = 0;
  auto alloc = [&](size_t bytes) {
    void* p = ws + off;
    off += (bytes + 255) & ~(size_t)255;
    return p;
  };
  float* support  = (float*)alloc((size_t)N_NODES * OUT_F * sizeof(float)); // 25.6MB
  int2*  csr      = (int2*)alloc((size_t)N_EDGES * sizeof(int2));           // 12.8MB
  int*   cnt      = (int*)alloc((size_t)N_NODES * sizeof(int));
  int*   row_ptr  = (int*)alloc((size_t)(N_NODES + 1) * sizeof(int));
  int*   cursor   = (int*)alloc((size_t)N_NODES * sizeof(int));
  int*   partials = (int*)alloc(256 * sizeof(int));
  int*   blockoff = (int*)alloc(256 * sizeof(int));

  hipMemsetAsync(cnt, 0, (size_t)N_NODES * sizeof(int), stream);

  gemm_support<<<2048, 256, 0, stream>>>(x, weight, support);
  histogram<<<4096, 256, 0, stream>>>(edst, cnt);
  scan_blocks<<<N_SCAN_BLKS, SCAN_BLK, 0, stream>>>(cnt, row_ptr, partials);
  scan_partials<<<1, 128, 0, stream>>>(partials, blockoff);
  add_offsets<<<N_SCAN_BLKS, SCAN_BLK, 0, stream>>>(row_ptr, cursor, blockoff);
  csr_scatter<<<4096, 256, 0, stream>>>(esrc, edst, ew, cursor, csr);
  gather<<<4096, 256, 0, stream>>>(support, csr, row_ptr, out);
  finalize<<<2048, 256, 0, stream>>>(x, bias, gamma, beta, res_w, res_b, out);
}